// Round 5
// baseline (76.714 us; speedup 1.0000x reference)
//
#include <hip/hip_runtime.h>

// privacyLoss1: result = (0.5/N) * sum_{i in [0,N-2], j in [1,N-1]} sign_ij * ||x_i - x_j||^2
// sign_ij = +1 if label_i == label_j else -1.
//
// Factorization: sign = 2*[same] - 1  =>  Total = 2*A - B with
//   A = sum_c [ nC_c*SsqR_c + nR_c*SsqC_c - 2*<VR_c, VC_c> ]
//   B = (N-1)*(SsqR + SsqC) - 2*<VR, VC>
// R = rows except N-1, C = rows except 0. All terms derive from full-set
// per-class stats (n_c, Ssq_c, V_c) + O(D) corrections with x_0, x_{N-1}.
// => O(N*D) streaming instead of O(N^2 D).
//
// v5: SINGLE kernel dispatch (+68-byte memset node for the counters).
// Phase A: (row-group g x dim-slice s) blocks, float4 loads, register
// per-class accum -> disjoint Vpart/Spart slabs (no atomics on data).
// Per-slice last block (device-scope counter + threadfence, rocPRIM pattern;
// NOT a CG grid barrier -- that measured ~50us/sync on 8 XCDs in v3):
// reduces its 640 V elements over G groups and collapses them to 44 scalars
// (VV_c, V0_c, VN_c, VVt, d0N, s0, sN, Ssq_c). Global last slice-reducer:
// sums 16x44 scalars + label counts + fp64 closed-form combine.
// "Who is last" varies per run, but all reductions are fixed-order loops /
// shfl trees over deterministic partials -> bitwise-identical result.

#define NCLS 10
#define SVST 48   // sliceVals stride (44 used, padded)

__device__ inline float wave_reduce64(float v) {
#pragma unroll
    for (int off = 32; off > 0; off >>= 1) v += __shfl_xor(v, off, 64);
    return v;
}

__global__ __launch_bounds__(256) void fused_kernel(
        const float* __restrict__ x, const int* __restrict__ label,
        float* __restrict__ Vpart, float* __restrict__ Spart,
        float* __restrict__ sliceVals, unsigned int* __restrict__ counters,
        float* __restrict__ result,
        int N, int D, int S, int G, int rpb) {
    const int t = threadIdx.x;
    const int b = blockIdx.x;
    const int s = b % S;                // 64-float dim slice
    const int g = b / S;                // row group
    const int row0 = g * rpb;
    const int rows = min(rpb, N - row0);
    const int lane = t & 63;
    const int w = t >> 6;

    // ================= phase A: per-(group,slice) partials =================
    __shared__ int labs[512];
    for (int r = t; r < rows; r += 256) labs[r] = label[row0 + r];
    __syncthreads();

    const int sub = t >> 4;   // 0..15 row phase
    const int l16 = t & 15;   // float4 slot in 64-float slice

    float4 vacc[NCLS];
    float  sacc[NCLS];
#pragma unroll
    for (int c = 0; c < NCLS; ++c) {
        vacc[c] = make_float4(0.f, 0.f, 0.f, 0.f);
        sacc[c] = 0.f;
    }

    const float* bp = x + (size_t)row0 * D + s * 64 + l16 * 4;
#pragma unroll 4
    for (int r = sub; r < rows; r += 16) {
        float4 v = *(const float4*)(bp + (size_t)r * D);
        int l = labs[r];
        float sq = v.x * v.x + v.y * v.y + v.z * v.z + v.w * v.w;
#pragma unroll
        for (int c = 0; c < NCLS; ++c) {
            float m = (l == c) ? 1.0f : 0.0f;
            vacc[c].x = fmaf(m, v.x, vacc[c].x);
            vacc[c].y = fmaf(m, v.y, vacc[c].y);
            vacc[c].z = fmaf(m, v.z, vacc[c].z);
            vacc[c].w = fmaf(m, v.w, vacc[c].w);
            sacc[c]   = fmaf(m, sq, sacc[c]);
        }
    }

    // reduce row-phase lane bits 4,5 for vacc; whole wave for sacc
#pragma unroll
    for (int c = 0; c < NCLS; ++c) {
        vacc[c].x += __shfl_xor(vacc[c].x, 16, 64);
        vacc[c].y += __shfl_xor(vacc[c].y, 16, 64);
        vacc[c].z += __shfl_xor(vacc[c].z, 16, 64);
        vacc[c].w += __shfl_xor(vacc[c].w, 16, 64);
        vacc[c].x += __shfl_xor(vacc[c].x, 32, 64);
        vacc[c].y += __shfl_xor(vacc[c].y, 32, 64);
        vacc[c].z += __shfl_xor(vacc[c].z, 32, 64);
        vacc[c].w += __shfl_xor(vacc[c].w, 32, 64);
        sacc[c] = wave_reduce64(sacc[c]);
    }

    __shared__ float lsv[4][NCLS][64];
    __shared__ float lss[4][NCLS];
    if (lane < 16) {
#pragma unroll
        for (int c = 0; c < NCLS; ++c)
            *(float4*)&lsv[w][c][l16 * 4] = vacc[c];
    }
    if (lane == 0) {
#pragma unroll
        for (int c = 0; c < NCLS; ++c) lss[w][c] = sacc[c];
    }
    __syncthreads();

    for (int e = t; e < NCLS * 64; e += 256) {
        int c = e >> 6, dd = e & 63;
        float vs = lsv[0][c][dd] + lsv[1][c][dd] + lsv[2][c][dd] + lsv[3][c][dd];
        Vpart[((size_t)g * NCLS + c) * D + s * 64 + dd] = vs;
    }
    if (t < NCLS)
        Spart[(size_t)b * NCLS + t] =
            lss[0][t] + lss[1][t] + lss[2][t] + lss[3][t];
    __syncthreads();

    // ============ slice-level completion (last of G blocks) ============
    __threadfence();
    __shared__ int lastS;
    if (t == 0) lastS = (atomicAdd(&counters[s], 1u) == (unsigned)(G - 1)) ? 1 : 0;
    __syncthreads();
    if (!lastS) return;
    __threadfence();   // acquire: see all G blocks' Vpart/Spart writes

    // wave w owns classes {w, w+4, w+8} (exactly covers 0..9 across 4 waves);
    // lane = dim within slice.
    const int dglob = s * 64 + lane;
    const float a0 = x[dglob];
    const float aN = x[(size_t)(N - 1) * D + dglob];

    float vsum[3];
    float vt = 0.f;
#pragma unroll
    for (int i = 0; i < 3; ++i) {
        int c = w + 4 * i;
        float acc = 0.f;
        if (c < NCLS) {
            for (int g2 = 0; g2 < G; ++g2)
                acc += Vpart[((size_t)g2 * NCLS + c) * D + dglob];
        }
        vsum[i] = acc;
        vt += acc;
    }

    __shared__ float vtl[4][64];
    vtl[w][lane] = vt;
    __syncthreads();

    float* sv = sliceVals + (size_t)s * SVST;
#pragma unroll
    for (int i = 0; i < 3; ++i) {
        int c = w + 4 * i;
        if (c < NCLS) {
            float vv = wave_reduce64(vsum[i] * vsum[i]);
            float v0 = wave_reduce64(vsum[i] * a0);
            float vn = wave_reduce64(vsum[i] * aN);
            if (lane == 0) {
                sv[c]          = vv;
                sv[10 + c]     = v0;
                sv[20 + c]     = vn;
            }
        }
    }
    if (w == 0) {
        float vta = vtl[0][lane] + vtl[1][lane] + vtl[2][lane] + vtl[3][lane];
        float vvt = wave_reduce64(vta * vta);
        float dn  = wave_reduce64(a0 * aN);
        float s0v = wave_reduce64(a0 * a0);
        float sNv = wave_reduce64(aN * aN);
        if (lane == 0) { sv[30] = vvt; sv[31] = dn; sv[32] = s0v; sv[33] = sNv; }
    }
    if (w == 1) {
        // Ssq_c contribution of this slice: sum Spart over its G blocks
#pragma unroll
        for (int c = 0; c < NCLS; ++c) {
            float v = (lane < G) ? Spart[((size_t)lane * S + s) * NCLS + c] : 0.f;
            v = wave_reduce64(v);
            if (lane == 0) sv[34 + c] = v;
        }
    }
    __syncthreads();

    // ============ global completion (last of S slice-reducers) ============
    __threadfence();
    __shared__ int lastG;
    if (t == 0) lastG = (atomicAdd(&counters[S], 1u) == (unsigned)(S - 1)) ? 1 : 0;
    __syncthreads();
    if (!lastG) return;
    __threadfence();   // acquire: see all slices' sliceVals writes

    // ---- label counts ----
    float cnt[NCLS];
#pragma unroll
    for (int c = 0; c < NCLS; ++c) cnt[c] = 0.f;
    for (int i = t; i < N; i += 256) {
        int l = label[i];
#pragma unroll
        for (int c = 0; c < NCLS; ++c) cnt[c] += (l == c) ? 1.0f : 0.0f;
    }
    __shared__ float lcnt[4][NCLS];
#pragma unroll
    for (int c = 0; c < NCLS; ++c) {
        float v = wave_reduce64(cnt[c]);
        if (lane == 0) lcnt[w][c] = v;
    }

    // ---- sum per-slice scalars (fp64) ----
    __shared__ double fin[44];
    if (t < 44) {
        double acc = 0.0;
        for (int s2 = 0; s2 < S; ++s2)
            acc += (double)sliceVals[(size_t)s2 * SVST + t];
        fin[t] = acc;
    }
    __syncthreads();

    if (t == 0) {
        const int l0 = label[0];
        const int lN = label[N - 1];
        const double VVtd = fin[30], dON = fin[31], sq0 = fin[32], sqN = fin[33];

        double A = 0.0, SsqTot = 0.0, Vt0 = 0.0, VtN = 0.0;
        for (int c = 0; c < NCLS; ++c) {
            double nc   = (double)(lcnt[0][c] + lcnt[1][c] + lcnt[2][c] + lcnt[3][c]);
            double Ssqc = fin[34 + c];
            SsqTot += Ssqc;
            Vt0    += fin[10 + c];
            VtN    += fin[20 + c];
            double ac = (lN == c) ? 1.0 : 0.0;  // excluded from rows R
            double bc = (l0 == c) ? 1.0 : 0.0;  // excluded from cols C
            double nR = nc - ac, nC = nc - bc;
            double SsqR  = Ssqc - ac * sqN;
            double SsqC  = Ssqc - bc * sq0;
            double dotRC = fin[c] - bc * fin[10 + c] - ac * fin[20 + c] + ac * bc * dON;
            A += nC * SsqR + nR * SsqC - 2.0 * dotRC;
        }
        double Bv = (double)(N - 1) * ((SsqTot - sqN) + (SsqTot - sq0))
                  - 2.0 * (VVtd - Vt0 - VtN + dON);
        double total = 2.0 * A - Bv;
        result[0] = (float)((0.5 / (double)N) * total);
    }
}

// ------------------ fallback: v1 atomic path (tiny ws) ------------------
__global__ __launch_bounds__(256) void zero_ws_kernel(float* __restrict__ p, int n) {
    int i = blockIdx.x * 256 + threadIdx.x;
    if (i < n) p[i] = 0.0f;
}

__global__ __launch_bounds__(256) void accum_kernel(
        const float* __restrict__ x, const int* __restrict__ label,
        float* __restrict__ V, float* __restrict__ Ssq,
        int N, int D, int dimSlices, int rowsPerChunk) {
    const int t  = threadIdx.x;
    const int ds = blockIdx.x % dimSlices;
    const int rc = blockIdx.x / dimSlices;
    const int row0 = rc * rowsPerChunk;

    __shared__ int labs[64];
    if (t < rowsPerChunk && row0 + t < N) labs[t] = label[row0 + t];
    __syncthreads();

    const int d = ds * 256 + t;
    float vacc[NCLS], sacc[NCLS];
#pragma unroll
    for (int c = 0; c < NCLS; ++c) { vacc[c] = 0.0f; sacc[c] = 0.0f; }

    const float* p = x + (size_t)row0 * D + d;
    const int rows = (row0 + rowsPerChunk <= N) ? rowsPerChunk : (N - row0);
    for (int r = 0; r < rows; ++r) {
        float v = p[(size_t)r * D];
        int   l = labs[r];
        float sq = v * v;
#pragma unroll
        for (int c = 0; c < NCLS; ++c) {
            float m = (l == c) ? 1.0f : 0.0f;
            vacc[c] = fmaf(m, v, vacc[c]);
            sacc[c] = fmaf(m, sq, sacc[c]);
        }
    }
#pragma unroll
    for (int c = 0; c < NCLS; ++c) atomicAdd(&V[c * D + d], vacc[c]);
    const int lane = t & 63;
#pragma unroll
    for (int c = 0; c < NCLS; ++c) {
        float v = wave_reduce64(sacc[c]);
        if (lane == 0) atomicAdd(&Ssq[c], v);
    }
}

__global__ __launch_bounds__(256) void finalize_small_kernel(
        const float* __restrict__ x, const int* __restrict__ label,
        const float* __restrict__ V, const float* __restrict__ Ssq,
        float* __restrict__ result, int N, int D) {
    const int t    = threadIdx.x;
    const int lane = t & 63;
    const int wave = t >> 6;

    float VV[NCLS], V0[NCLS], VN[NCLS];
#pragma unroll
    for (int c = 0; c < NCLS; ++c) { VV[c] = 0.0f; V0[c] = 0.0f; VN[c] = 0.0f; }
    float VVt = 0.0f, d0N = 0.0f, s0 = 0.0f, sN = 0.0f;

    const float* x0 = x;
    const float* xN = x + (size_t)(N - 1) * D;
    for (int d = t; d < D; d += 256) {
        float a0 = x0[d], aN = xN[d];
        float vt = 0.0f;
#pragma unroll
        for (int c = 0; c < NCLS; ++c) {
            float v = V[c * D + d];
            VV[c] += v * v;
            V0[c] += v * a0;
            VN[c] += v * aN;
            vt    += v;
        }
        VVt += vt * vt;
        d0N += a0 * aN;
        s0  += a0 * a0;
        sN  += aN * aN;
    }

    float vals[34];
#pragma unroll
    for (int c = 0; c < NCLS; ++c) {
        vals[c]      = VV[c];
        vals[10 + c] = V0[c];
        vals[20 + c] = VN[c];
    }
    vals[30] = VVt; vals[31] = d0N; vals[32] = s0; vals[33] = sN;

    __shared__ float red[4][34];
#pragma unroll
    for (int k = 0; k < 34; ++k) {
        float v = wave_reduce64(vals[k]);
        if (lane == 0) red[wave][k] = v;
    }
    __syncthreads();

    if (t == 0) {
        double v[34];
        for (int k = 0; k < 34; ++k)
            v[k] = (double)red[0][k] + (double)red[1][k] + (double)red[2][k] + (double)red[3][k];

        float cnt2[NCLS];
#pragma unroll
        for (int c = 0; c < NCLS; ++c) cnt2[c] = 0.f;
        for (int i = 0; i < N; ++i) {
            int l = label[i];
#pragma unroll
            for (int c = 0; c < NCLS; ++c) cnt2[c] += (l == c) ? 1.0f : 0.0f;
        }

        const int l0 = label[0];
        const int lN = label[N - 1];
        const double sq0 = v[32], sqN = v[33], dON = v[31], VVtd = v[30];

        double A = 0.0, SsqTot = 0.0, Vt0 = 0.0, VtN = 0.0;
        for (int c = 0; c < NCLS; ++c) {
            double nc   = (double)cnt2[c];
            double Ssqc = (double)Ssq[c];
            SsqTot += Ssqc;
            Vt0    += v[10 + c];
            VtN    += v[20 + c];
            double ac = (lN == c) ? 1.0 : 0.0;
            double bc = (l0 == c) ? 1.0 : 0.0;
            double nR = nc - ac, nC = nc - bc;
            double SsqR  = Ssqc - ac * sqN;
            double SsqC  = Ssqc - bc * sq0;
            double dotRC = v[c] - bc * v[10 + c] - ac * v[20 + c] + ac * bc * dON;
            A += nC * SsqR + nR * SsqC - 2.0 * dotRC;
        }
        double Bv = (double)(N - 1) * ((SsqTot - sqN) + (SsqTot - sq0))
                  - 2.0 * (VVtd - Vt0 - VtN + dON);
        double total = 2.0 * A - Bv;
        result[0] = (float)((0.5 / (double)N) * total);
    }
}

extern "C" void kernel_launch(void* const* d_in, const int* in_sizes, int n_in,
                              void* d_out, int out_size, void* d_ws, size_t ws_size,
                              hipStream_t stream) {
    const float* x     = (const float*)d_in[0];
    const int*   label = (const int*)d_in[1];
    const int N = in_sizes[1];
    const int D = in_sizes[0] / N;   // 1024
    float* result = (float*)d_out;

    const size_t wsFloats = ws_size / sizeof(float);

    // ---- main path: memset node + ONE fused kernel ----
    const int rpb = 128;
    bool ok = (D % 64 == 0);
    int S = 0, G = 0, gridA = 0;
    size_t need = 0;
    if (ok) {
        S = D / 64;                      // 16 for D=1024
        G = (N + rpb - 1) / rpb;         // 32 for N=4096
        gridA = G * S;                   // 512
        ok = (G <= 64) && (rpb <= 512);
        need = (size_t)G * NCLS * D      // Vpart
             + (size_t)gridA * NCLS      // Spart
             + (size_t)S * SVST          // sliceVals
             + (S + 1) + 16;             // counters (+pad)
        ok = ok && (need <= wsFloats);
    }

    if (ok) {
        float* Vpart = (float*)d_ws;
        float* Spart = Vpart + (size_t)G * NCLS * D;
        float* sliceVals = Spart + (size_t)gridA * NCLS;
        unsigned int* counters = (unsigned int*)(sliceVals + (size_t)S * SVST);

        hipMemsetAsync(counters, 0, (S + 1) * sizeof(unsigned int), stream);
        fused_kernel<<<gridA, 256, 0, stream>>>(
            x, label, Vpart, Spart, sliceVals, counters, result,
            N, D, S, G, rpb);
        return;
    }

    // ---- fallback: v1 atomic path (needs ~41 KB ws) ----
    float* V   = (float*)d_ws;
    float* Ssq = V + NCLS * D;
    const int nz = NCLS * D + NCLS;
    zero_ws_kernel<<<(nz + 255) / 256, 256, 0, stream>>>(V, nz);
    const int rowsPerChunk = 64;
    const int dimSlices = (D + 255) / 256;
    const int rowChunks = (N + rowsPerChunk - 1) / rowsPerChunk;
    accum_kernel<<<rowChunks * dimSlices, 256, 0, stream>>>(
        x, label, V, Ssq, N, D, dimSlices, rowsPerChunk);
    finalize_small_kernel<<<1, 256, 0, stream>>>(x, label, V, Ssq, result, N, D);
}

// Round 6
// 45.348 us; speedup vs baseline: 1.6917x; 1.6917x over previous
//
#include <hip/hip_runtime.h>

// privacyLoss1: result = (0.5/N) * sum_{i in [0,N-2], j in [1,N-1]} sign_ij * ||x_i - x_j||^2
// sign_ij = +1 if label_i == label_j else -1.
//
// Factorization: sign = 2*[same] - 1  =>  Total = 2*A - B with
//   A = sum_c [ nC_c*SsqR_c + nR_c*SsqC_c - 2*<VR_c, VC_c> ]
//   B = (N-1)*(SsqR + SsqC) - 2*<VR, VC>
// R = rows except N-1, C = rows except 0. All terms derive from full-set
// per-class stats (n_c, Ssq_c, V_c) + O(D) corrections with x_0, x_{N-1}.
// => O(N*D) streaming instead of O(N^2 D).
//
// v6: ONE kernel dispatch + one 41KB memset node.
// Phase A blocks (row-group g x dim-slice s) accumulate per-class partials in
// registers (float4 loads), LDS-reduce, then flush with DEVICE-SCOPE atomicAdd
// directly into V[10][D]/Ssq[10]. Atomics execute at the coherence point -> no
// dirty L2 lines -> release needs only `s_waitcnt vmcnt(0)` (cheap), NOT
// __threadfence() per block (v5's 512 L2-writeback fences cost ~70us).
// Last block (done-counter) does one acquire threadfence, label counts, the
// V-derived dot products, and the fp64 closed-form combine.
// fp32 atomic ordering varies run-to-run (~1e-5 rel); same work every call.

#define NCLS 10
#define NV3  34   // 10 VV + 10 V0 + 10 VN + VVt,d0N,s0,sN

__device__ inline float wave_reduce64(float v) {
#pragma unroll
    for (int off = 32; off > 0; off >>= 1) v += __shfl_xor(v, off, 64);
    return v;
}

__global__ __launch_bounds__(256) void main_kernel(
        const float* __restrict__ x, const int* __restrict__ label,
        float* __restrict__ V, float* __restrict__ Ssq,
        unsigned int* __restrict__ done, float* __restrict__ result,
        int N, int D, int S, int rpb, int fused, int nBlocks) {
    const int t = threadIdx.x;
    const int b = blockIdx.x;
    const int s = b % S;                // 64-float dim slice
    const int g = b / S;                // row group
    const int row0 = g * rpb;
    const int rows = min(rpb, N - row0);
    const int lane = t & 63;
    const int w = t >> 6;

    // ================= phase A: per-(group,slice) partials =================
    __shared__ int labs[512];
    for (int r = t; r < rows; r += 256) labs[r] = label[row0 + r];
    __syncthreads();

    const int sub = t >> 4;   // 0..15 row phase
    const int l16 = t & 15;   // float4 slot in 64-float slice

    float4 vacc[NCLS];
    float  sacc[NCLS];
#pragma unroll
    for (int c = 0; c < NCLS; ++c) {
        vacc[c] = make_float4(0.f, 0.f, 0.f, 0.f);
        sacc[c] = 0.f;
    }

    const float* bp = x + (size_t)row0 * D + s * 64 + l16 * 4;
#pragma unroll 4
    for (int r = sub; r < rows; r += 16) {
        float4 v = *(const float4*)(bp + (size_t)r * D);
        int l = labs[r];
        float sq = v.x * v.x + v.y * v.y + v.z * v.z + v.w * v.w;
#pragma unroll
        for (int c = 0; c < NCLS; ++c) {
            float m = (l == c) ? 1.0f : 0.0f;
            vacc[c].x = fmaf(m, v.x, vacc[c].x);
            vacc[c].y = fmaf(m, v.y, vacc[c].y);
            vacc[c].z = fmaf(m, v.z, vacc[c].z);
            vacc[c].w = fmaf(m, v.w, vacc[c].w);
            sacc[c]   = fmaf(m, sq, sacc[c]);
        }
    }

    // reduce row-phase lane bits 4,5 for vacc; whole wave for sacc
#pragma unroll
    for (int c = 0; c < NCLS; ++c) {
        vacc[c].x += __shfl_xor(vacc[c].x, 16, 64);
        vacc[c].y += __shfl_xor(vacc[c].y, 16, 64);
        vacc[c].z += __shfl_xor(vacc[c].z, 16, 64);
        vacc[c].w += __shfl_xor(vacc[c].w, 16, 64);
        vacc[c].x += __shfl_xor(vacc[c].x, 32, 64);
        vacc[c].y += __shfl_xor(vacc[c].y, 32, 64);
        vacc[c].z += __shfl_xor(vacc[c].z, 32, 64);
        vacc[c].w += __shfl_xor(vacc[c].w, 32, 64);
        sacc[c] = wave_reduce64(sacc[c]);
    }

    __shared__ float lsv[4][NCLS][64];
    __shared__ float lss[4][NCLS];
    if (lane < 16) {
#pragma unroll
        for (int c = 0; c < NCLS; ++c)
            *(float4*)&lsv[w][c][l16 * 4] = vacc[c];
    }
    if (lane == 0) {
#pragma unroll
        for (int c = 0; c < NCLS; ++c) lss[w][c] = sacc[c];
    }
    __syncthreads();

    // flush: device-scope atomics straight to V/Ssq (coalesced, 32 adds/addr)
    for (int e = t; e < NCLS * 64; e += 256) {
        int c = e >> 6, dd = e & 63;
        float vs = lsv[0][c][dd] + lsv[1][c][dd] + lsv[2][c][dd] + lsv[3][c][dd];
        atomicAdd(&V[c * D + s * 64 + dd], vs);
    }
    if (t < NCLS)
        atomicAdd(&Ssq[t], lss[0][t] + lss[1][t] + lss[2][t] + lss[3][t]);

    if (!fused) return;

    // ============ completion: last of nBlocks runs the combine ============
    // Atomics complete at the coherence point; vmcnt(0) orders them before
    // the counter increment. No L2-writeback fence needed (no plain stores).
    asm volatile("s_waitcnt vmcnt(0)" ::: "memory");
    __shared__ int isLast;
    if (t == 0) isLast = (atomicAdd(done, 1u) == (unsigned)(nBlocks - 1)) ? 1 : 0;
    __syncthreads();
    if (!isLast) return;
    __threadfence();   // acquire: observe all blocks' V/Ssq atomics

    // ---- label counts ----
    float cnt[NCLS];
#pragma unroll
    for (int c = 0; c < NCLS; ++c) cnt[c] = 0.f;
    for (int i = t; i < N; i += 256) {
        int l = label[i];
#pragma unroll
        for (int c = 0; c < NCLS; ++c) cnt[c] += (l == c) ? 1.0f : 0.0f;
    }
    __shared__ float lcnt[4][NCLS];
#pragma unroll
    for (int c = 0; c < NCLS; ++c) {
        float v = wave_reduce64(cnt[c]);
        if (lane == 0) lcnt[w][c] = v;
    }

    // ---- V-derived dot products ----
    float VV[NCLS], V0[NCLS], VN[NCLS];
#pragma unroll
    for (int c = 0; c < NCLS; ++c) { VV[c] = 0.f; V0[c] = 0.f; VN[c] = 0.f; }
    float VVt = 0.f, d0N = 0.f, s0 = 0.f, sN = 0.f;

    const float* x0 = x;
    const float* xN = x + (size_t)(N - 1) * D;
    for (int d = t; d < D; d += 256) {
        float a0 = x0[d], aN = xN[d];
        float vt = 0.f;
#pragma unroll
        for (int c = 0; c < NCLS; ++c) {
            float v = V[c * D + d];
            VV[c] += v * v;
            V0[c] += v * a0;
            VN[c] += v * aN;
            vt    += v;
        }
        VVt += vt * vt;
        d0N += a0 * aN;
        s0  += a0 * a0;
        sN  += aN * aN;
    }

    float vals[NV3];
#pragma unroll
    for (int c = 0; c < NCLS; ++c) {
        vals[c]      = VV[c];
        vals[10 + c] = V0[c];
        vals[20 + c] = VN[c];
    }
    vals[30] = VVt; vals[31] = d0N; vals[32] = s0; vals[33] = sN;

    __shared__ float red[4][NV3];
#pragma unroll
    for (int k = 0; k < NV3; ++k) {
        float v = wave_reduce64(vals[k]);
        if (lane == 0) red[w][k] = v;
    }
    __syncthreads();

    if (t == 0) {
        double v[NV3];
        for (int k = 0; k < NV3; ++k)
            v[k] = (double)red[0][k] + (double)red[1][k] + (double)red[2][k] + (double)red[3][k];

        const int l0 = label[0];
        const int lN = label[N - 1];
        const double sq0 = v[32], sqN = v[33], dON = v[31], VVtd = v[30];

        double A = 0.0, SsqTot = 0.0, Vt0 = 0.0, VtN = 0.0;
        for (int c = 0; c < NCLS; ++c) {
            double nc   = (double)(lcnt[0][c] + lcnt[1][c] + lcnt[2][c] + lcnt[3][c]);
            double Ssqc = (double)Ssq[c];
            SsqTot += Ssqc;
            Vt0    += v[10 + c];
            VtN    += v[20 + c];
            double ac = (lN == c) ? 1.0 : 0.0;  // excluded from rows R
            double bc = (l0 == c) ? 1.0 : 0.0;  // excluded from cols C
            double nR = nc - ac, nC = nc - bc;
            double SsqR  = Ssqc - ac * sqN;
            double SsqC  = Ssqc - bc * sq0;
            double dotRC = v[c] - bc * v[10 + c] - ac * v[20 + c] + ac * bc * dON;
            A += nC * SsqR + nR * SsqC - 2.0 * dotRC;
        }
        double Bv = (double)(N - 1) * ((SsqTot - sqN) + (SsqTot - sq0))
                  - 2.0 * (VVtd - Vt0 - VtN + dON);
        double total = 2.0 * A - Bv;
        result[0] = (float)((0.5 / (double)N) * total);
    }
}

// ---- fallback finalize (separate dispatch) for the non-fused path ----
__global__ __launch_bounds__(256) void finalize_small_kernel(
        const float* __restrict__ x, const int* __restrict__ label,
        const float* __restrict__ V, const float* __restrict__ Ssq,
        float* __restrict__ result, int N, int D) {
    const int t    = threadIdx.x;
    const int lane = t & 63;
    const int wave = t >> 6;

    float cnt[NCLS];
#pragma unroll
    for (int c = 0; c < NCLS; ++c) cnt[c] = 0.f;
    for (int i = t; i < N; i += 256) {
        int l = label[i];
#pragma unroll
        for (int c = 0; c < NCLS; ++c) cnt[c] += (l == c) ? 1.0f : 0.0f;
    }
    __shared__ float lcnt[4][NCLS];
#pragma unroll
    for (int c = 0; c < NCLS; ++c) {
        float v = wave_reduce64(cnt[c]);
        if (lane == 0) lcnt[wave][c] = v;
    }

    float VV[NCLS], V0[NCLS], VN[NCLS];
#pragma unroll
    for (int c = 0; c < NCLS; ++c) { VV[c] = 0.f; V0[c] = 0.f; VN[c] = 0.f; }
    float VVt = 0.f, d0N = 0.f, s0 = 0.f, sN = 0.f;

    const float* x0 = x;
    const float* xN = x + (size_t)(N - 1) * D;
    for (int d = t; d < D; d += 256) {
        float a0 = x0[d], aN = xN[d];
        float vt = 0.f;
#pragma unroll
        for (int c = 0; c < NCLS; ++c) {
            float v = V[c * D + d];
            VV[c] += v * v;
            V0[c] += v * a0;
            VN[c] += v * aN;
            vt    += v;
        }
        VVt += vt * vt;
        d0N += a0 * aN;
        s0  += a0 * a0;
        sN  += aN * aN;
    }

    float vals[NV3];
#pragma unroll
    for (int c = 0; c < NCLS; ++c) {
        vals[c]      = VV[c];
        vals[10 + c] = V0[c];
        vals[20 + c] = VN[c];
    }
    vals[30] = VVt; vals[31] = d0N; vals[32] = s0; vals[33] = sN;

    __shared__ float red[4][NV3];
#pragma unroll
    for (int k = 0; k < NV3; ++k) {
        float v = wave_reduce64(vals[k]);
        if (lane == 0) red[wave][k] = v;
    }
    __syncthreads();

    if (t == 0) {
        double v[NV3];
        for (int k = 0; k < NV3; ++k)
            v[k] = (double)red[0][k] + (double)red[1][k] + (double)red[2][k] + (double)red[3][k];

        const int l0 = label[0];
        const int lN = label[N - 1];
        const double sq0 = v[32], sqN = v[33], dON = v[31], VVtd = v[30];

        double A = 0.0, SsqTot = 0.0, Vt0 = 0.0, VtN = 0.0;
        for (int c = 0; c < NCLS; ++c) {
            double nc   = (double)(lcnt[0][c] + lcnt[1][c] + lcnt[2][c] + lcnt[3][c]);
            double Ssqc = (double)Ssq[c];
            SsqTot += Ssqc;
            Vt0    += v[10 + c];
            VtN    += v[20 + c];
            double ac = (lN == c) ? 1.0 : 0.0;
            double bc = (l0 == c) ? 1.0 : 0.0;
            double nR = nc - ac, nC = nc - bc;
            double SsqR  = Ssqc - ac * sqN;
            double SsqC  = Ssqc - bc * sq0;
            double dotRC = v[c] - bc * v[10 + c] - ac * v[20 + c] + ac * bc * dON;
            A += nC * SsqR + nR * SsqC - 2.0 * dotRC;
        }
        double Bv = (double)(N - 1) * ((SsqTot - sqN) + (SsqTot - sq0))
                  - 2.0 * (VVtd - Vt0 - VtN + dON);
        double total = 2.0 * A - Bv;
        result[0] = (float)((0.5 / (double)N) * total);
    }
}

extern "C" void kernel_launch(void* const* d_in, const int* in_sizes, int n_in,
                              void* d_out, int out_size, void* d_ws, size_t ws_size,
                              hipStream_t stream) {
    const float* x     = (const float*)d_in[0];
    const int*   label = (const int*)d_in[1];
    const int N = in_sizes[1];
    const int D = in_sizes[0] / N;   // 1024
    float* result = (float*)d_out;

    const size_t wsFloats = ws_size / sizeof(float);

    // ws layout: V[NCLS*D] | Ssq[NCLS] | done (1 u32)  -- all zeroed per call
    const size_t needF = (size_t)NCLS * D + NCLS + 1;
    float* V   = (float*)d_ws;
    float* Ssq = V + (size_t)NCLS * D;
    unsigned int* done = (unsigned int*)(Ssq + NCLS);

    int rpb = 128;
    bool fusedOK = (D % 64 == 0) && (needF <= wsFloats) && (N > rpb);
    const int S = (D % 64 == 0) ? D / 64 : 0;

    if (fusedOK) {
        const int G = (N + rpb - 1) / rpb;   // 32 for N=4096
        const int gridA = G * S;             // 512
        hipMemsetAsync(d_ws, 0, needF * sizeof(float), stream);
        main_kernel<<<gridA, 256, 0, stream>>>(
            x, label, V, Ssq, done, result, N, D, S, rpb, 1, gridA);
        return;
    }

    // ---- fallback: same accumulation, separate finalize dispatch ----
    if (S > 0 && needF <= wsFloats) {
        const int G = (N + rpb - 1) / rpb;
        const int gridA = G * S;
        hipMemsetAsync(d_ws, 0, needF * sizeof(float), stream);
        main_kernel<<<gridA, 256, 0, stream>>>(
            x, label, V, Ssq, done, result, N, D, S, rpb, 0, gridA);
        finalize_small_kernel<<<1, 256, 0, stream>>>(x, label, V, Ssq, result, N, D);
    }
}

// Round 7
// 36.636 us; speedup vs baseline: 2.0939x; 1.2378x over previous
//
#include <hip/hip_runtime.h>

// privacyLoss1: result = (0.5/N) * sum_{i in [0,N-2], j in [1,N-1]} sign_ij * ||x_i - x_j||^2
// sign_ij = +1 if label_i == label_j else -1.
//
// Factorization: sign = 2*[same] - 1  =>  Total = 2*A - B with
//   A = sum_c [ nC_c*SsqR_c + nR_c*SsqC_c - 2*<VR_c, VC_c> ]
//   B = (N-1)*(SsqR + SsqC) - 2*<VR, VC>
// R = rows except N-1, C = rows except 0. All terms derive from full-set
// per-class stats (n_c, Ssq_c, V_c) + O(D) corrections with x_0, x_{N-1}.
// => O(N*D) streaming instead of O(N^2 D).
//
// v7: ONE kernel + one 41KB memset node. Fixes v6's tail:
//  - Ssq 512-way same-address fp32 atomic hot-spot (~12us of serialized LLC
//    RMWs) -> disjoint per-block Spart slots via packed u64 atomicExch
//    (no contention, no init, no dirty L2 lines).
//  - label counts fused into phase A (LDS histogram in the s==0 blocks +
//    10 int atomicAdds each) so the finisher doesn't stream 16KB of labels.
//  - V flush stays fp32 atomicAdd (32-way/address, parallel across 640
//    addresses, ~2us). Release = s_waitcnt vmcnt(0) only (atomics complete
//    at the coherence point; v5 showed per-block __threadfence = ~70us of
//    L2 writebacks when plain stores are in flight -- here there are none).

#define NCLS 10
#define NV3  34   // 10 VV + 10 V0 + 10 VN + VVt,d0N,s0,sN

__device__ inline float wave_reduce64(float v) {
#pragma unroll
    for (int off = 32; off > 0; off >>= 1) v += __shfl_xor(v, off, 64);
    return v;
}

__device__ inline unsigned long long pack2(float a, float b) {
    return (unsigned long long)__float_as_uint(a) |
           ((unsigned long long)__float_as_uint(b) << 32);
}

__global__ __launch_bounds__(256) void main_kernel(
        const float* __restrict__ x, const int* __restrict__ label,
        float* __restrict__ V, unsigned long long* __restrict__ Spart,
        int* __restrict__ icnt, unsigned int* __restrict__ done,
        float* __restrict__ result,
        int N, int D, int S, int rpb, int fused, int nBlocks) {
    const int t = threadIdx.x;
    const int b = blockIdx.x;
    const int s = b % S;                // 64-float dim slice
    const int g = b / S;                // row group
    const int row0 = g * rpb;
    const int rows = min(rpb, N - row0);
    const int lane = t & 63;
    const int w = t >> 6;

    // ================= phase A: per-(group,slice) partials =================
    __shared__ int labs[512];
    __shared__ int hist[NCLS];
    if (s == 0 && t < NCLS) hist[t] = 0;
    for (int r = t; r < rows; r += 256) labs[r] = label[row0 + r];
    __syncthreads();

    // label histogram: one block per row-group (s==0) via LDS atomics
    if (s == 0) {
        for (int r = t; r < rows; r += 256) atomicAdd(&hist[labs[r]], 1);
    }

    const int sub = t >> 4;   // 0..15 row phase
    const int l16 = t & 15;   // float4 slot in 64-float slice

    float4 vacc[NCLS];
    float  sacc[NCLS];
#pragma unroll
    for (int c = 0; c < NCLS; ++c) {
        vacc[c] = make_float4(0.f, 0.f, 0.f, 0.f);
        sacc[c] = 0.f;
    }

    const float* bp = x + (size_t)row0 * D + s * 64 + l16 * 4;
#pragma unroll 4
    for (int r = sub; r < rows; r += 16) {
        float4 v = *(const float4*)(bp + (size_t)r * D);
        int l = labs[r];
        float sq = v.x * v.x + v.y * v.y + v.z * v.z + v.w * v.w;
#pragma unroll
        for (int c = 0; c < NCLS; ++c) {
            float m = (l == c) ? 1.0f : 0.0f;
            vacc[c].x = fmaf(m, v.x, vacc[c].x);
            vacc[c].y = fmaf(m, v.y, vacc[c].y);
            vacc[c].z = fmaf(m, v.z, vacc[c].z);
            vacc[c].w = fmaf(m, v.w, vacc[c].w);
            sacc[c]   = fmaf(m, sq, sacc[c]);
        }
    }

    // reduce row-phase lane bits 4,5 for vacc; whole wave for sacc
#pragma unroll
    for (int c = 0; c < NCLS; ++c) {
        vacc[c].x += __shfl_xor(vacc[c].x, 16, 64);
        vacc[c].y += __shfl_xor(vacc[c].y, 16, 64);
        vacc[c].z += __shfl_xor(vacc[c].z, 16, 64);
        vacc[c].w += __shfl_xor(vacc[c].w, 16, 64);
        vacc[c].x += __shfl_xor(vacc[c].x, 32, 64);
        vacc[c].y += __shfl_xor(vacc[c].y, 32, 64);
        vacc[c].z += __shfl_xor(vacc[c].z, 32, 64);
        vacc[c].w += __shfl_xor(vacc[c].w, 32, 64);
        sacc[c] = wave_reduce64(sacc[c]);
    }

    __shared__ float lsv[4][NCLS][64];
    __shared__ float lss[4][NCLS];
    if (lane < 16) {
#pragma unroll
        for (int c = 0; c < NCLS; ++c)
            *(float4*)&lsv[w][c][l16 * 4] = vacc[c];
    }
    if (lane == 0) {
#pragma unroll
        for (int c = 0; c < NCLS; ++c) lss[w][c] = sacc[c];
    }
    __syncthreads();

    // V flush: fp32 atomicAdd, coalesced, disjoint across slices (32 adds/addr)
    for (int e = t; e < NCLS * 64; e += 256) {
        int c = e >> 6, dd = e & 63;
        float vs = lsv[0][c][dd] + lsv[1][c][dd] + lsv[2][c][dd] + lsv[3][c][dd];
        atomicAdd(&V[c * D + s * 64 + dd], vs);
    }
    // Ssq flush: disjoint per-block slots, packed u64 atomicExch (no init, no
    // contention, bypasses L2 -> no release fence needed)
    if (t < NCLS / 2) {
        int c0 = 2 * t, c1 = 2 * t + 1;
        float a = lss[0][c0] + lss[1][c0] + lss[2][c0] + lss[3][c0];
        float bb = lss[0][c1] + lss[1][c1] + lss[2][c1] + lss[3][c1];
        atomicExch(&Spart[(size_t)b * (NCLS / 2) + t], pack2(a, bb));
    }
    // label counts: integer adds (deterministic), 32-way contention only
    if (s == 0 && t < NCLS) atomicAdd(&icnt[t], hist[t]);

    if (!fused) return;

    // ============ completion: last of nBlocks runs the combine ============
    asm volatile("s_waitcnt vmcnt(0)" ::: "memory");
    __shared__ int isLast;
    if (t == 0) isLast = (atomicAdd(done, 1u) == (unsigned)(nBlocks - 1)) ? 1 : 0;
    __syncthreads();
    if (!isLast) return;
    __threadfence();   // acquire; cheap: no dirty L2 lines exist (atomics only)

    // ---- Ssq from Spart ----
    float sp[NCLS];
#pragma unroll
    for (int c = 0; c < NCLS; ++c) sp[c] = 0.f;
    const float* SpF = (const float*)Spart;
    for (int i = t; i < nBlocks; i += 256) {
#pragma unroll
        for (int c = 0; c < NCLS; ++c) sp[c] += SpF[(size_t)i * NCLS + c];
    }

    // ---- V-derived dot products ----
    float VV[NCLS], V0[NCLS], VN[NCLS];
#pragma unroll
    for (int c = 0; c < NCLS; ++c) { VV[c] = 0.f; V0[c] = 0.f; VN[c] = 0.f; }
    float VVt = 0.f, d0N = 0.f, s0 = 0.f, sN = 0.f;

    const float* x0 = x;
    const float* xN = x + (size_t)(N - 1) * D;
    for (int d = t; d < D; d += 256) {
        float a0 = x0[d], aN = xN[d];
        float vt = 0.f;
#pragma unroll
        for (int c = 0; c < NCLS; ++c) {
            float v = V[c * D + d];
            VV[c] += v * v;
            V0[c] += v * a0;
            VN[c] += v * aN;
            vt    += v;
        }
        VVt += vt * vt;
        d0N += a0 * aN;
        s0  += a0 * a0;
        sN  += aN * aN;
    }

    float vals[NV3];
#pragma unroll
    for (int c = 0; c < NCLS; ++c) {
        vals[c]      = VV[c];
        vals[10 + c] = V0[c];
        vals[20 + c] = VN[c];
    }
    vals[30] = VVt; vals[31] = d0N; vals[32] = s0; vals[33] = sN;

    __shared__ float red[4][NV3];
    __shared__ float rss[4][NCLS];
#pragma unroll
    for (int k = 0; k < NV3; ++k) {
        float v = wave_reduce64(vals[k]);
        if (lane == 0) red[w][k] = v;
    }
#pragma unroll
    for (int c = 0; c < NCLS; ++c) {
        float v = wave_reduce64(sp[c]);
        if (lane == 0) rss[w][c] = v;
    }
    __syncthreads();

    if (t == 0) {
        double v[NV3];
        for (int k = 0; k < NV3; ++k)
            v[k] = (double)red[0][k] + (double)red[1][k] + (double)red[2][k] + (double)red[3][k];

        const int l0 = label[0];
        const int lN = label[N - 1];
        const double sq0 = v[32], sqN = v[33], dON = v[31], VVtd = v[30];

        double A = 0.0, SsqTot = 0.0, Vt0 = 0.0, VtN = 0.0;
        for (int c = 0; c < NCLS; ++c) {
            double nc   = (double)icnt[c];
            double Ssqc = (double)(rss[0][c] + rss[1][c] + rss[2][c] + rss[3][c]);
            SsqTot += Ssqc;
            Vt0    += v[10 + c];
            VtN    += v[20 + c];
            double ac = (lN == c) ? 1.0 : 0.0;  // excluded from rows R
            double bc = (l0 == c) ? 1.0 : 0.0;  // excluded from cols C
            double nR = nc - ac, nC = nc - bc;
            double SsqR  = Ssqc - ac * sqN;
            double SsqC  = Ssqc - bc * sq0;
            double dotRC = v[c] - bc * v[10 + c] - ac * v[20 + c] + ac * bc * dON;
            A += nC * SsqR + nR * SsqC - 2.0 * dotRC;
        }
        double Bv = (double)(N - 1) * ((SsqTot - sqN) + (SsqTot - sq0))
                  - 2.0 * (VVtd - Vt0 - VtN + dON);
        double total = 2.0 * A - Bv;
        result[0] = (float)((0.5 / (double)N) * total);
    }
}

// ---- fallback finalize (separate dispatch) for the non-fused path ----
__global__ __launch_bounds__(256) void finalize_small_kernel(
        const float* __restrict__ x, const int* __restrict__ label,
        const float* __restrict__ V, const unsigned long long* __restrict__ Spart,
        const int* __restrict__ icnt, int nBlocks,
        float* __restrict__ result, int N, int D) {
    const int t    = threadIdx.x;
    const int lane = t & 63;
    const int w    = t >> 6;

    float sp[NCLS];
#pragma unroll
    for (int c = 0; c < NCLS; ++c) sp[c] = 0.f;
    const float* SpF = (const float*)Spart;
    for (int i = t; i < nBlocks; i += 256) {
#pragma unroll
        for (int c = 0; c < NCLS; ++c) sp[c] += SpF[(size_t)i * NCLS + c];
    }

    float VV[NCLS], V0[NCLS], VN[NCLS];
#pragma unroll
    for (int c = 0; c < NCLS; ++c) { VV[c] = 0.f; V0[c] = 0.f; VN[c] = 0.f; }
    float VVt = 0.f, d0N = 0.f, s0 = 0.f, sN = 0.f;

    const float* x0 = x;
    const float* xN = x + (size_t)(N - 1) * D;
    for (int d = t; d < D; d += 256) {
        float a0 = x0[d], aN = xN[d];
        float vt = 0.f;
#pragma unroll
        for (int c = 0; c < NCLS; ++c) {
            float v = V[c * D + d];
            VV[c] += v * v;
            V0[c] += v * a0;
            VN[c] += v * aN;
            vt    += v;
        }
        VVt += vt * vt;
        d0N += a0 * aN;
        s0  += a0 * a0;
        sN  += aN * aN;
    }

    float vals[NV3];
#pragma unroll
    for (int c = 0; c < NCLS; ++c) {
        vals[c]      = VV[c];
        vals[10 + c] = V0[c];
        vals[20 + c] = VN[c];
    }
    vals[30] = VVt; vals[31] = d0N; vals[32] = s0; vals[33] = sN;

    __shared__ float red[4][NV3];
    __shared__ float rss[4][NCLS];
#pragma unroll
    for (int k = 0; k < NV3; ++k) {
        float v = wave_reduce64(vals[k]);
        if (lane == 0) red[w][k] = v;
    }
#pragma unroll
    for (int c = 0; c < NCLS; ++c) {
        float v = wave_reduce64(sp[c]);
        if (lane == 0) rss[w][c] = v;
    }
    __syncthreads();

    if (t == 0) {
        double v[NV3];
        for (int k = 0; k < NV3; ++k)
            v[k] = (double)red[0][k] + (double)red[1][k] + (double)red[2][k] + (double)red[3][k];

        const int l0 = label[0];
        const int lN = label[N - 1];
        const double sq0 = v[32], sqN = v[33], dON = v[31], VVtd = v[30];

        double A = 0.0, SsqTot = 0.0, Vt0 = 0.0, VtN = 0.0;
        for (int c = 0; c < NCLS; ++c) {
            double nc   = (double)icnt[c];
            double Ssqc = (double)(rss[0][c] + rss[1][c] + rss[2][c] + rss[3][c]);
            SsqTot += Ssqc;
            Vt0    += v[10 + c];
            VtN    += v[20 + c];
            double ac = (lN == c) ? 1.0 : 0.0;
            double bc = (l0 == c) ? 1.0 : 0.0;
            double nR = nc - ac, nC = nc - bc;
            double SsqR  = Ssqc - ac * sqN;
            double SsqC  = Ssqc - bc * sq0;
            double dotRC = v[c] - bc * v[10 + c] - ac * v[20 + c] + ac * bc * dON;
            A += nC * SsqR + nR * SsqC - 2.0 * dotRC;
        }
        double Bv = (double)(N - 1) * ((SsqTot - sqN) + (SsqTot - sq0))
                  - 2.0 * (VVtd - Vt0 - VtN + dON);
        double total = 2.0 * A - Bv;
        result[0] = (float)((0.5 / (double)N) * total);
    }
}

extern "C" void kernel_launch(void* const* d_in, const int* in_sizes, int n_in,
                              void* d_out, int out_size, void* d_ws, size_t ws_size,
                              hipStream_t stream) {
    const float* x     = (const float*)d_in[0];
    const int*   label = (const int*)d_in[1];
    const int N = in_sizes[1];
    const int D = in_sizes[0] / N;   // 1024
    float* result = (float*)d_out;

    // ws layout (memset covers the prefix [V | icnt | done]):
    //   V[NCLS*D] f32 | icnt[16] i32 | done u32 | pad | Spart[nBlocks*5] u64
    const int rpb = 128;
    const int S = (D % 64 == 0) ? D / 64 : 0;
    const int G = (N + rpb - 1) / rpb;
    const int gridA = G * S;

    float* V = (float*)d_ws;
    int*   icnt = (int*)(V + (size_t)NCLS * D);
    unsigned int* done = (unsigned int*)(icnt + 16);
    size_t zeroBytes = (size_t)NCLS * D * 4 + 16 * 4 + 4;
    size_t spartOff = (zeroBytes + 7) & ~(size_t)7;
    unsigned long long* Spart = (unsigned long long*)((char*)d_ws + spartOff);

    size_t needBytes = spartOff + (size_t)gridA * (NCLS / 2) * 8;
    bool ok = (S > 0) && (N >= 2) && (needBytes <= ws_size);

    if (ok) {
        hipMemsetAsync(d_ws, 0, zeroBytes, stream);
        main_kernel<<<gridA, 256, 0, stream>>>(
            x, label, V, Spart, icnt, done, result, N, D, S, rpb, 1, gridA);
        return;
    }

    // ---- fallback: same accumulation, separate finalize dispatch ----
    if (S > 0 && needBytes <= ws_size + 0) {
        // unreachable given above, kept for shape safety
    }
    if (S > 0) {
        hipMemsetAsync(d_ws, 0, zeroBytes, stream);
        main_kernel<<<gridA, 256, 0, stream>>>(
            x, label, V, Spart, icnt, done, result, N, D, S, rpb, 0, gridA);
        finalize_small_kernel<<<1, 256, 0, stream>>>(
            x, label, V, Spart, icnt, gridA, result, N, D);
    }
}

// Round 8
// 25.048 us; speedup vs baseline: 3.0627x; 1.4626x over previous
//
#include <hip/hip_runtime.h>

// privacyLoss1: result = (0.5/N) * sum_{i in [0,N-2], j in [1,N-1]} sign_ij * ||x_i - x_j||^2
// sign_ij = +1 if label_i == label_j else -1.
//
// Factorization: sign = 2*[same] - 1  =>  Total = 2*A - B with
//   A = sum_c [ nC_c*SsqR_c + nR_c*SsqC_c - 2*<VR_c, VC_c> ]
//   B = (N-1)*(SsqR + SsqC) - 2*<VR, VC>
// R = rows except N-1, C = rows except 0. All terms derive from full-set
// per-class stats (n_c, Ssq_c, V_c) + O(D) corrections with x_0, x_{N-1}.
// => O(N*D) streaming instead of O(N^2 D).
//
// v8: two dispatches (the structural floor: 1-node needs zeroed counters, but
// the harness poisons ws before replay 1 and forbids cross-call state).
//  node1 phaseA: (row-group x dim-slice) float4 partials + label histogram ->
//    disjoint plain stores (Vpart/Spart/hist). Resets done. Deterministic.
//  node2 finish (S+1=17 blocks): block s<16 reduces its slice over G groups
//    and collapses straight to 44 slice scalars (VV_c,V0_c,VN_c,VVt,d0N,s0,
//    sN,0) -- no V array, no big last-block re-read. Block 16 sums Spart+hist.
//    Last block (counter+threadfence; cheap at 17 blocks -- v5 showed 512
//    fences cost ~70us) sums 17x44 scalars in fp64 and combines.
// All reductions fixed-order -> bitwise-deterministic output.

#define NCLS 10
#define SLOTW 64   // per-block scalar slot stride (44 used)
#define NV3  34

__device__ inline float wave_reduce64(float v) {
#pragma unroll
    for (int off = 32; off > 0; off >>= 1) v += __shfl_xor(v, off, 64);
    return v;
}

// ---------------- node 1: per-(group,slice) partial stats ----------------
__global__ __launch_bounds__(256) void phaseA_kernel(
        const float* __restrict__ x, const int* __restrict__ label,
        float* __restrict__ Vpart, float* __restrict__ Spart,
        int* __restrict__ hist, unsigned int* __restrict__ done,
        int N, int D, int S, int rpb) {
    const int t = threadIdx.x;
    const int b = blockIdx.x;
    if (b == 0 && t == 0) *done = 0u;   // reset for node 2 (kernel boundary)

    const int s = b % S;                // 64-float dim slice
    const int g = b / S;                // row group
    const int row0 = g * rpb;
    const int rows = min(rpb, N - row0);
    const int lane = t & 63;
    const int w = t >> 6;

    __shared__ int labs[512];
    __shared__ int lh[NCLS];
    if (t < NCLS) lh[t] = 0;
    for (int r = t; r < rows; r += 256) labs[r] = label[row0 + r];
    __syncthreads();

    if (s == 0) {   // one block per row-group does the label histogram
        for (int r = t; r < rows; r += 256) atomicAdd(&lh[labs[r]], 1);
    }

    const int sub = t >> 4;   // 0..15 row phase
    const int l16 = t & 15;   // float4 slot in 64-float slice

    float4 vacc[NCLS];
    float  sacc[NCLS];
#pragma unroll
    for (int c = 0; c < NCLS; ++c) {
        vacc[c] = make_float4(0.f, 0.f, 0.f, 0.f);
        sacc[c] = 0.f;
    }

    const float* bp = x + (size_t)row0 * D + s * 64 + l16 * 4;
#pragma unroll 4
    for (int r = sub; r < rows; r += 16) {
        float4 v = *(const float4*)(bp + (size_t)r * D);
        int l = labs[r];
        float sq = v.x * v.x + v.y * v.y + v.z * v.z + v.w * v.w;
#pragma unroll
        for (int c = 0; c < NCLS; ++c) {
            float m = (l == c) ? 1.0f : 0.0f;
            vacc[c].x = fmaf(m, v.x, vacc[c].x);
            vacc[c].y = fmaf(m, v.y, vacc[c].y);
            vacc[c].z = fmaf(m, v.z, vacc[c].z);
            vacc[c].w = fmaf(m, v.w, vacc[c].w);
            sacc[c]   = fmaf(m, sq, sacc[c]);
        }
    }

    // reduce row-phase lane bits 4,5 for vacc; whole wave for sacc
#pragma unroll
    for (int c = 0; c < NCLS; ++c) {
        vacc[c].x += __shfl_xor(vacc[c].x, 16, 64);
        vacc[c].y += __shfl_xor(vacc[c].y, 16, 64);
        vacc[c].z += __shfl_xor(vacc[c].z, 16, 64);
        vacc[c].w += __shfl_xor(vacc[c].w, 16, 64);
        vacc[c].x += __shfl_xor(vacc[c].x, 32, 64);
        vacc[c].y += __shfl_xor(vacc[c].y, 32, 64);
        vacc[c].z += __shfl_xor(vacc[c].z, 32, 64);
        vacc[c].w += __shfl_xor(vacc[c].w, 32, 64);
        sacc[c] = wave_reduce64(sacc[c]);
    }

    __shared__ float lsv[4][NCLS][64];
    __shared__ float lss[4][NCLS];
    if (lane < 16) {
#pragma unroll
        for (int c = 0; c < NCLS; ++c)
            *(float4*)&lsv[w][c][l16 * 4] = vacc[c];
    }
    if (lane == 0) {
#pragma unroll
        for (int c = 0; c < NCLS; ++c) lss[w][c] = sacc[c];
    }
    __syncthreads();

    // disjoint plain stores (coalesced 256B chunks per wave)
    for (int e = t; e < NCLS * 64; e += 256) {
        int c = e >> 6, dd = e & 63;
        float vs = lsv[0][c][dd] + lsv[1][c][dd] + lsv[2][c][dd] + lsv[3][c][dd];
        Vpart[((size_t)g * NCLS + c) * D + s * 64 + dd] = vs;
    }
    if (t < NCLS)
        Spart[(size_t)b * NCLS + t] =
            lss[0][t] + lss[1][t] + lss[2][t] + lss[3][t];
    if (s == 0 && t < NCLS) hist[g * NCLS + t] = lh[t];
}

// ------- node 2: slice-scalar reduce + last-block fp64 combine -------
__global__ __launch_bounds__(256) void finish_kernel(
        const float* __restrict__ x, const int* __restrict__ label,
        const float* __restrict__ Vpart, const float* __restrict__ Spart,
        const int* __restrict__ hist,
        float* __restrict__ slots, float* __restrict__ cntF,
        unsigned int* __restrict__ done, float* __restrict__ result,
        int N, int D, int S, int G, int nSpart) {
    const int t = threadIdx.x;
    const int b = blockIdx.x;
    const int lane = t & 63;
    const int w = t >> 6;

    if (b < S) {
        // ---- slice reducer: complete V for 64 dims, collapse to scalars ----
        const int dglob = b * 64 + lane;
        const float a0 = x[dglob];
        const float aN = x[(size_t)(N - 1) * D + dglob];

        float vsum[3];
        float vt = 0.f;
#pragma unroll
        for (int i = 0; i < 3; ++i) {
            int c = w + 4 * i;
            float acc = 0.f;
            if (c < NCLS) {
#pragma unroll 4
                for (int g2 = 0; g2 < G; ++g2)
                    acc += Vpart[((size_t)g2 * NCLS + c) * D + dglob];
            }
            vsum[i] = acc;
            vt += acc;
        }

        __shared__ float vtl[4][64];
        vtl[w][lane] = vt;
        __syncthreads();

        float* sv = slots + (size_t)b * SLOTW;
#pragma unroll
        for (int i = 0; i < 3; ++i) {
            int c = w + 4 * i;
            if (c < NCLS) {
                float vv = wave_reduce64(vsum[i] * vsum[i]);
                float v0 = wave_reduce64(vsum[i] * a0);
                float vn = wave_reduce64(vsum[i] * aN);
                if (lane == 0) { sv[c] = vv; sv[10 + c] = v0; sv[20 + c] = vn; }
            }
        }
        if (w == 0) {
            float vta = vtl[0][lane] + vtl[1][lane] + vtl[2][lane] + vtl[3][lane];
            float vvt = wave_reduce64(vta * vta);
            float dn  = wave_reduce64(a0 * aN);
            float s0v = wave_reduce64(a0 * a0);
            float sNv = wave_reduce64(aN * aN);
            if (lane == 0) { sv[30] = vvt; sv[31] = dn; sv[32] = s0v; sv[33] = sNv; }
        }
        if (t >= 34 && t < 44) sv[t] = 0.f;   // Ssq slots owned by block S
    } else {
        // ---- block S: Spart sum (Ssq_c) + label counts ----
        float sp[NCLS];
#pragma unroll
        for (int c = 0; c < NCLS; ++c) sp[c] = 0.f;
        for (int i = t; i < nSpart; i += 256) {
#pragma unroll
            for (int c = 0; c < NCLS; ++c) sp[c] += Spart[(size_t)i * NCLS + c];
        }
        __shared__ float rss[4][NCLS];
#pragma unroll
        for (int c = 0; c < NCLS; ++c) {
            float v = wave_reduce64(sp[c]);
            if (lane == 0) rss[w][c] = v;
        }
        __syncthreads();
        float* sv = slots + (size_t)S * SLOTW;
        if (t < 34) sv[t] = 0.f;
        if (t < NCLS) {
            sv[34 + t] = rss[0][t] + rss[1][t] + rss[2][t] + rss[3][t];
            int a = 0;
            for (int g2 = 0; g2 < G; ++g2) a += hist[g2 * NCLS + t];
            cntF[t] = (float)a;
        }
    }

    // ---- completion: last of S+1 blocks combines ----
    __threadfence();
    __shared__ int isLast;
    if (t == 0) isLast = (atomicAdd(done, 1u) == (unsigned)(gridDim.x - 1)) ? 1 : 0;
    __syncthreads();
    if (!isLast) return;
    __threadfence();

    __shared__ double fin[44];
    if (t < 44) {
        double a = 0.0;
        for (int bb = 0; bb <= S; ++bb) a += (double)slots[(size_t)bb * SLOTW + t];
        fin[t] = a;
    }
    __syncthreads();

    if (t == 0) {
        const int l0 = label[0];
        const int lN = label[N - 1];
        const double VVtd = fin[30], dON = fin[31], sq0 = fin[32], sqN = fin[33];

        double A = 0.0, SsqTot = 0.0, Vt0 = 0.0, VtN = 0.0;
        for (int c = 0; c < NCLS; ++c) {
            double nc   = (double)cntF[c];
            double Ssqc = fin[34 + c];
            SsqTot += Ssqc;
            Vt0    += fin[10 + c];
            VtN    += fin[20 + c];
            double ac = (lN == c) ? 1.0 : 0.0;  // excluded from rows R
            double bc = (l0 == c) ? 1.0 : 0.0;  // excluded from cols C
            double nR = nc - ac, nC = nc - bc;
            double SsqR  = Ssqc - ac * sqN;
            double SsqC  = Ssqc - bc * sq0;
            double dotRC = fin[c] - bc * fin[10 + c] - ac * fin[20 + c] + ac * bc * dON;
            A += nC * SsqR + nR * SsqC - 2.0 * dotRC;
        }
        double Bv = (double)(N - 1) * ((SsqTot - sqN) + (SsqTot - sq0))
                  - 2.0 * (VVtd - Vt0 - VtN + dON);
        double total = 2.0 * A - Bv;
        result[0] = (float)((0.5 / (double)N) * total);
    }
}

// ------------------ fallback: v1 atomic path (any shape) ------------------
__global__ __launch_bounds__(256) void zero_ws_kernel(float* __restrict__ p, int n) {
    int i = blockIdx.x * 256 + threadIdx.x;
    if (i < n) p[i] = 0.0f;
}

__global__ __launch_bounds__(256) void accum_kernel(
        const float* __restrict__ x, const int* __restrict__ label,
        float* __restrict__ V, float* __restrict__ Ssq,
        int N, int D, int dimSlices, int rowsPerChunk) {
    const int t  = threadIdx.x;
    const int ds = blockIdx.x % dimSlices;
    const int rc = blockIdx.x / dimSlices;
    const int row0 = rc * rowsPerChunk;

    __shared__ int labs[64];
    if (t < rowsPerChunk && row0 + t < N) labs[t] = label[row0 + t];
    __syncthreads();

    const int d = ds * 256 + t;
    if (d >= D) return;
    float vacc[NCLS], sacc[NCLS];
#pragma unroll
    for (int c = 0; c < NCLS; ++c) { vacc[c] = 0.0f; sacc[c] = 0.0f; }

    const float* p = x + (size_t)row0 * D + d;
    const int rows = (row0 + rowsPerChunk <= N) ? rowsPerChunk : (N - row0);
    for (int r = 0; r < rows; ++r) {
        float v = p[(size_t)r * D];
        int   l = labs[r];
        float sq = v * v;
#pragma unroll
        for (int c = 0; c < NCLS; ++c) {
            float m = (l == c) ? 1.0f : 0.0f;
            vacc[c] = fmaf(m, v, vacc[c]);
            sacc[c] = fmaf(m, sq, sacc[c]);
        }
    }
#pragma unroll
    for (int c = 0; c < NCLS; ++c) atomicAdd(&V[c * D + d], vacc[c]);
    const int lane = t & 63;
#pragma unroll
    for (int c = 0; c < NCLS; ++c) {
        float v = wave_reduce64(sacc[c]);
        if (lane == 0) atomicAdd(&Ssq[c], v);
    }
}

__global__ __launch_bounds__(256) void finalize_small_kernel(
        const float* __restrict__ x, const int* __restrict__ label,
        const float* __restrict__ V, const float* __restrict__ Ssq,
        float* __restrict__ result, int N, int D) {
    const int t    = threadIdx.x;
    const int lane = t & 63;
    const int wave = t >> 6;

    float cnt[NCLS];
#pragma unroll
    for (int c = 0; c < NCLS; ++c) cnt[c] = 0.f;
    for (int i = t; i < N; i += 256) {
        int l = label[i];
#pragma unroll
        for (int c = 0; c < NCLS; ++c) cnt[c] += (l == c) ? 1.0f : 0.0f;
    }
    __shared__ float lcnt[4][NCLS];
#pragma unroll
    for (int c = 0; c < NCLS; ++c) {
        float v = wave_reduce64(cnt[c]);
        if (lane == 0) lcnt[wave][c] = v;
    }

    float VV[NCLS], V0[NCLS], VN[NCLS];
#pragma unroll
    for (int c = 0; c < NCLS; ++c) { VV[c] = 0.f; V0[c] = 0.f; VN[c] = 0.f; }
    float VVt = 0.f, d0N = 0.f, s0 = 0.f, sN = 0.f;

    const float* x0 = x;
    const float* xN = x + (size_t)(N - 1) * D;
    for (int d = t; d < D; d += 256) {
        float a0 = x0[d], aN = xN[d];
        float vt = 0.f;
#pragma unroll
        for (int c = 0; c < NCLS; ++c) {
            float v = V[c * D + d];
            VV[c] += v * v;
            V0[c] += v * a0;
            VN[c] += v * aN;
            vt    += v;
        }
        VVt += vt * vt;
        d0N += a0 * aN;
        s0  += a0 * a0;
        sN  += aN * aN;
    }

    float vals[NV3];
#pragma unroll
    for (int c = 0; c < NCLS; ++c) {
        vals[c]      = VV[c];
        vals[10 + c] = V0[c];
        vals[20 + c] = VN[c];
    }
    vals[30] = VVt; vals[31] = d0N; vals[32] = s0; vals[33] = sN;

    __shared__ float red[4][NV3];
#pragma unroll
    for (int k = 0; k < NV3; ++k) {
        float v = wave_reduce64(vals[k]);
        if (lane == 0) red[wave][k] = v;
    }
    __syncthreads();

    if (t == 0) {
        double v[NV3];
        for (int k = 0; k < NV3; ++k)
            v[k] = (double)red[0][k] + (double)red[1][k] + (double)red[2][k] + (double)red[3][k];

        const int l0 = label[0];
        const int lN = label[N - 1];
        const double sq0 = v[32], sqN = v[33], dON = v[31], VVtd = v[30];

        double A = 0.0, SsqTot = 0.0, Vt0 = 0.0, VtN = 0.0;
        for (int c = 0; c < NCLS; ++c) {
            double nc   = (double)(lcnt[0][c] + lcnt[1][c] + lcnt[2][c] + lcnt[3][c]);
            double Ssqc = (double)Ssq[c];
            SsqTot += Ssqc;
            Vt0    += v[10 + c];
            VtN    += v[20 + c];
            double ac = (lN == c) ? 1.0 : 0.0;
            double bc = (l0 == c) ? 1.0 : 0.0;
            double nR = nc - ac, nC = nc - bc;
            double SsqR  = Ssqc - ac * sqN;
            double SsqC  = Ssqc - bc * sq0;
            double dotRC = v[c] - bc * v[10 + c] - ac * v[20 + c] + ac * bc * dON;
            A += nC * SsqR + nR * SsqC - 2.0 * dotRC;
        }
        double Bv = (double)(N - 1) * ((SsqTot - sqN) + (SsqTot - sq0))
                  - 2.0 * (VVtd - Vt0 - VtN + dON);
        double total = 2.0 * A - Bv;
        result[0] = (float)((0.5 / (double)N) * total);
    }
}

extern "C" void kernel_launch(void* const* d_in, const int* in_sizes, int n_in,
                              void* d_out, int out_size, void* d_ws, size_t ws_size,
                              hipStream_t stream) {
    const float* x     = (const float*)d_in[0];
    const int*   label = (const int*)d_in[1];
    const int N = in_sizes[1];
    const int D = in_sizes[0] / N;   // 1024
    float* result = (float*)d_out;

    const size_t wsFloats = ws_size / sizeof(float);
    const int rpb = 128;
    const int S = (D % 64 == 0) ? D / 64 : 0;
    const int G = (N + rpb - 1) / rpb;
    const int gridA = G * S;

    // ws layout (all plain-store fresh each call; no init needed):
    //   Vpart[G*NCLS*D] | Spart[gridA*NCLS] | hist[G*NCLS] i32 |
    //   cntF[16] | slots[(S+1)*SLOTW] | done u32
    size_t off = 0;
    float* Vpart = (float*)d_ws;                 off += (size_t)G * NCLS * D;
    float* Spart = (float*)d_ws + off;           off += (size_t)gridA * NCLS;
    int*   hist  = (int*)((float*)d_ws + off);   off += (size_t)G * NCLS;
    float* cntF  = (float*)d_ws + off;           off += 16;
    float* slots = (float*)d_ws + off;           off += (size_t)(S + 1) * SLOTW;
    unsigned int* done = (unsigned int*)((float*)d_ws + off); off += 1;

    bool ok = (S > 0) && (N >= 2) && (off <= wsFloats) && (G >= 1);

    if (ok) {
        phaseA_kernel<<<gridA, 256, 0, stream>>>(
            x, label, Vpart, Spart, hist, done, N, D, S, rpb);
        finish_kernel<<<S + 1, 256, 0, stream>>>(
            x, label, Vpart, Spart, hist, slots, cntF, done, result,
            N, D, S, G, gridA);
        return;
    }

    // ---- fallback: v1 atomic path (tiny ws / odd D) ----
    float* V   = (float*)d_ws;
    float* Ssq = V + (size_t)NCLS * D;
    const int nz = NCLS * D + NCLS;
    zero_ws_kernel<<<(nz + 255) / 256, 256, 0, stream>>>(V, nz);
    const int rowsPerChunk = 64;
    const int dimSlices = (D + 255) / 256;
    const int rowChunks = (N + rowsPerChunk - 1) / rowsPerChunk;
    accum_kernel<<<rowChunks * dimSlices, 256, 0, stream>>>(
        x, label, V, Ssq, N, D, dimSlices, rowsPerChunk);
    finalize_small_kernel<<<1, 256, 0, stream>>>(x, label, V, Ssq, result, N, D);
}

// Round 9
// 24.663 us; speedup vs baseline: 3.1104x; 1.0156x over previous
//
#include <hip/hip_runtime.h>

// privacyLoss1: result = (0.5/N) * sum_{i in [0,N-2], j in [1,N-1]} sign_ij * ||x_i - x_j||^2
// sign_ij = +1 if label_i == label_j else -1.
//
// Factorization: sign = 2*[same] - 1  =>  Total = 2*A - B with
//   A = sum_c [ nC_c*SsqR_c + nR_c*SsqC_c - 2*<VR_c, VC_c> ]
//   B = (N-1)*(SsqR + SsqC) - 2*<VR, VC>
// R = rows except N-1, C = rows except 0. All terms derive from full-set
// per-class stats (n_c, Ssq_c, V_c) + O(D) corrections with x_0, x_{N-1}.
// => O(N*D) streaming instead of O(N^2 D).
//
// v9 = v8 + batched-MLP phase A. v8's unroll-4 interleave left phaseA
// latency-bound (~2.5-3 TB/s at 2 waves/SIMD). v9 issues all 8 float4 loads
// back-to-back into registers (8 VMEM in flight/thread -> 64/CU) before any
// FMA consumes them, then accumulates. Rest identical to v8:
//  node1 phaseA: disjoint plain stores Vpart/Spart/hist, resets done.
//  node2 finish (S+1 blocks): per-slice collapse to 44 scalars; block S sums
//    Spart+hist; last block (counter, cheap at 17 blocks) fp64-combines.
// All reductions fixed-order -> bitwise-deterministic output.

#define NCLS 10
#define SLOTW 64   // per-block scalar slot stride (44 used)
#define NV3  34

__device__ inline float wave_reduce64(float v) {
#pragma unroll
    for (int off = 32; off > 0; off >>= 1) v += __shfl_xor(v, off, 64);
    return v;
}

// ---------------- node 1: per-(group,slice) partial stats ----------------
__global__ __launch_bounds__(256) void phaseA_kernel(
        const float* __restrict__ x, const int* __restrict__ label,
        float* __restrict__ Vpart, float* __restrict__ Spart,
        int* __restrict__ hist, unsigned int* __restrict__ done,
        int N, int D, int S, int rpb) {
    const int t = threadIdx.x;
    const int b = blockIdx.x;
    if (b == 0 && t == 0) *done = 0u;   // reset for node 2 (kernel boundary)

    const int s = b % S;                // 64-float dim slice
    const int g = b / S;                // row group
    const int row0 = g * rpb;
    const int rows = min(rpb, N - row0);
    const int lane = t & 63;
    const int w = t >> 6;

    __shared__ int labs[512];
    __shared__ int lh[NCLS];
    if (t < NCLS) lh[t] = 0;
    for (int r = t; r < rows; r += 256) labs[r] = label[row0 + r];
    __syncthreads();

    if (s == 0) {   // one block per row-group does the label histogram
        for (int r = t; r < rows; r += 256) atomicAdd(&lh[labs[r]], 1);
    }

    const int sub = t >> 4;   // 0..15 row phase
    const int l16 = t & 15;   // float4 slot in 64-float slice

    float4 vacc[NCLS];
    float  sacc[NCLS];
#pragma unroll
    for (int c = 0; c < NCLS; ++c) {
        vacc[c] = make_float4(0.f, 0.f, 0.f, 0.f);
        sacc[c] = 0.f;
    }

    const float* bp = x + (size_t)row0 * D + s * 64 + l16 * 4;

    if (rows == 128) {
        // fast path: batch-issue all 8 loads, THEN accumulate (8 VMEM in flight)
        float4 v[8];
        int    l[8];
#pragma unroll
        for (int i = 0; i < 8; ++i) {
            int r = sub + 16 * i;
            v[i] = *(const float4*)(bp + (size_t)r * D);
            l[i] = labs[r];
        }
#pragma unroll
        for (int i = 0; i < 8; ++i) {
            float sq = v[i].x * v[i].x + v[i].y * v[i].y
                     + v[i].z * v[i].z + v[i].w * v[i].w;
#pragma unroll
            for (int c = 0; c < NCLS; ++c) {
                float m = (l[i] == c) ? 1.0f : 0.0f;
                vacc[c].x = fmaf(m, v[i].x, vacc[c].x);
                vacc[c].y = fmaf(m, v[i].y, vacc[c].y);
                vacc[c].z = fmaf(m, v[i].z, vacc[c].z);
                vacc[c].w = fmaf(m, v[i].w, vacc[c].w);
                sacc[c]   = fmaf(m, sq, sacc[c]);
            }
        }
    } else {
        for (int r = sub; r < rows; r += 16) {
            float4 v = *(const float4*)(bp + (size_t)r * D);
            int l = labs[r];
            float sq = v.x * v.x + v.y * v.y + v.z * v.z + v.w * v.w;
#pragma unroll
            for (int c = 0; c < NCLS; ++c) {
                float m = (l == c) ? 1.0f : 0.0f;
                vacc[c].x = fmaf(m, v.x, vacc[c].x);
                vacc[c].y = fmaf(m, v.y, vacc[c].y);
                vacc[c].z = fmaf(m, v.z, vacc[c].z);
                vacc[c].w = fmaf(m, v.w, vacc[c].w);
                sacc[c]   = fmaf(m, sq, sacc[c]);
            }
        }
    }

    // reduce row-phase lane bits 4,5 for vacc; whole wave for sacc
#pragma unroll
    for (int c = 0; c < NCLS; ++c) {
        vacc[c].x += __shfl_xor(vacc[c].x, 16, 64);
        vacc[c].y += __shfl_xor(vacc[c].y, 16, 64);
        vacc[c].z += __shfl_xor(vacc[c].z, 16, 64);
        vacc[c].w += __shfl_xor(vacc[c].w, 16, 64);
        vacc[c].x += __shfl_xor(vacc[c].x, 32, 64);
        vacc[c].y += __shfl_xor(vacc[c].y, 32, 64);
        vacc[c].z += __shfl_xor(vacc[c].z, 32, 64);
        vacc[c].w += __shfl_xor(vacc[c].w, 32, 64);
        sacc[c] = wave_reduce64(sacc[c]);
    }

    __shared__ float lsv[4][NCLS][64];
    __shared__ float lss[4][NCLS];
    if (lane < 16) {
#pragma unroll
        for (int c = 0; c < NCLS; ++c)
            *(float4*)&lsv[w][c][l16 * 4] = vacc[c];
    }
    if (lane == 0) {
#pragma unroll
        for (int c = 0; c < NCLS; ++c) lss[w][c] = sacc[c];
    }
    __syncthreads();

    // disjoint plain stores (coalesced 256B chunks per wave)
    for (int e = t; e < NCLS * 64; e += 256) {
        int c = e >> 6, dd = e & 63;
        float vs = lsv[0][c][dd] + lsv[1][c][dd] + lsv[2][c][dd] + lsv[3][c][dd];
        Vpart[((size_t)g * NCLS + c) * D + s * 64 + dd] = vs;
    }
    if (t < NCLS)
        Spart[(size_t)b * NCLS + t] =
            lss[0][t] + lss[1][t] + lss[2][t] + lss[3][t];
    if (s == 0 && t < NCLS) hist[g * NCLS + t] = lh[t];
}

// ------- node 2: slice-scalar reduce + last-block fp64 combine -------
__global__ __launch_bounds__(256) void finish_kernel(
        const float* __restrict__ x, const int* __restrict__ label,
        const float* __restrict__ Vpart, const float* __restrict__ Spart,
        const int* __restrict__ hist,
        float* __restrict__ slots, float* __restrict__ cntF,
        unsigned int* __restrict__ done, float* __restrict__ result,
        int N, int D, int S, int G, int nSpart) {
    const int t = threadIdx.x;
    const int b = blockIdx.x;
    const int lane = t & 63;
    const int w = t >> 6;

    if (b < S) {
        // ---- slice reducer: complete V for 64 dims, collapse to scalars ----
        const int dglob = b * 64 + lane;
        const float a0 = x[dglob];
        const float aN = x[(size_t)(N - 1) * D + dglob];

        float vsum[3];
        float vt = 0.f;
#pragma unroll
        for (int i = 0; i < 3; ++i) {
            int c = w + 4 * i;
            float acc = 0.f;
            if (c < NCLS) {
#pragma unroll 4
                for (int g2 = 0; g2 < G; ++g2)
                    acc += Vpart[((size_t)g2 * NCLS + c) * D + dglob];
            }
            vsum[i] = acc;
            vt += acc;
        }

        __shared__ float vtl[4][64];
        vtl[w][lane] = vt;
        __syncthreads();

        float* sv = slots + (size_t)b * SLOTW;
#pragma unroll
        for (int i = 0; i < 3; ++i) {
            int c = w + 4 * i;
            if (c < NCLS) {
                float vv = wave_reduce64(vsum[i] * vsum[i]);
                float v0 = wave_reduce64(vsum[i] * a0);
                float vn = wave_reduce64(vsum[i] * aN);
                if (lane == 0) { sv[c] = vv; sv[10 + c] = v0; sv[20 + c] = vn; }
            }
        }
        if (w == 0) {
            float vta = vtl[0][lane] + vtl[1][lane] + vtl[2][lane] + vtl[3][lane];
            float vvt = wave_reduce64(vta * vta);
            float dn  = wave_reduce64(a0 * aN);
            float s0v = wave_reduce64(a0 * a0);
            float sNv = wave_reduce64(aN * aN);
            if (lane == 0) { sv[30] = vvt; sv[31] = dn; sv[32] = s0v; sv[33] = sNv; }
        }
        if (t >= 34 && t < 44) sv[t] = 0.f;   // Ssq slots owned by block S
    } else {
        // ---- block S: Spart sum (Ssq_c) + label counts ----
        float sp[NCLS];
#pragma unroll
        for (int c = 0; c < NCLS; ++c) sp[c] = 0.f;
        for (int i = t; i < nSpart; i += 256) {
#pragma unroll
            for (int c = 0; c < NCLS; ++c) sp[c] += Spart[(size_t)i * NCLS + c];
        }
        __shared__ float rss[4][NCLS];
#pragma unroll
        for (int c = 0; c < NCLS; ++c) {
            float v = wave_reduce64(sp[c]);
            if (lane == 0) rss[w][c] = v;
        }
        __syncthreads();
        float* sv = slots + (size_t)S * SLOTW;
        if (t < 34) sv[t] = 0.f;
        if (t < NCLS) {
            sv[34 + t] = rss[0][t] + rss[1][t] + rss[2][t] + rss[3][t];
            int a = 0;
            for (int g2 = 0; g2 < G; ++g2) a += hist[g2 * NCLS + t];
            cntF[t] = (float)a;
        }
    }

    // ---- completion: last of S+1 blocks combines ----
    __threadfence();
    __shared__ int isLast;
    if (t == 0) isLast = (atomicAdd(done, 1u) == (unsigned)(gridDim.x - 1)) ? 1 : 0;
    __syncthreads();
    if (!isLast) return;
    __threadfence();

    __shared__ double fin[44];
    if (t < 44) {
        double a = 0.0;
        for (int bb = 0; bb <= S; ++bb) a += (double)slots[(size_t)bb * SLOTW + t];
        fin[t] = a;
    }
    __syncthreads();

    if (t == 0) {
        const int l0 = label[0];
        const int lN = label[N - 1];
        const double VVtd = fin[30], dON = fin[31], sq0 = fin[32], sqN = fin[33];

        double A = 0.0, SsqTot = 0.0, Vt0 = 0.0, VtN = 0.0;
        for (int c = 0; c < NCLS; ++c) {
            double nc   = (double)cntF[c];
            double Ssqc = fin[34 + c];
            SsqTot += Ssqc;
            Vt0    += fin[10 + c];
            VtN    += fin[20 + c];
            double ac = (lN == c) ? 1.0 : 0.0;  // excluded from rows R
            double bc = (l0 == c) ? 1.0 : 0.0;  // excluded from cols C
            double nR = nc - ac, nC = nc - bc;
            double SsqR  = Ssqc - ac * sqN;
            double SsqC  = Ssqc - bc * sq0;
            double dotRC = fin[c] - bc * fin[10 + c] - ac * fin[20 + c] + ac * bc * dON;
            A += nC * SsqR + nR * SsqC - 2.0 * dotRC;
        }
        double Bv = (double)(N - 1) * ((SsqTot - sqN) + (SsqTot - sq0))
                  - 2.0 * (VVtd - Vt0 - VtN + dON);
        double total = 2.0 * A - Bv;
        result[0] = (float)((0.5 / (double)N) * total);
    }
}

// ------------------ fallback: v1 atomic path (any shape) ------------------
__global__ __launch_bounds__(256) void zero_ws_kernel(float* __restrict__ p, int n) {
    int i = blockIdx.x * 256 + threadIdx.x;
    if (i < n) p[i] = 0.0f;
}

__global__ __launch_bounds__(256) void accum_kernel(
        const float* __restrict__ x, const int* __restrict__ label,
        float* __restrict__ V, float* __restrict__ Ssq,
        int N, int D, int dimSlices, int rowsPerChunk) {
    const int t  = threadIdx.x;
    const int ds = blockIdx.x % dimSlices;
    const int rc = blockIdx.x / dimSlices;
    const int row0 = rc * rowsPerChunk;

    __shared__ int labs[64];
    if (t < rowsPerChunk && row0 + t < N) labs[t] = label[row0 + t];
    __syncthreads();

    const int d = ds * 256 + t;
    if (d >= D) return;
    float vacc[NCLS], sacc[NCLS];
#pragma unroll
    for (int c = 0; c < NCLS; ++c) { vacc[c] = 0.0f; sacc[c] = 0.0f; }

    const float* p = x + (size_t)row0 * D + d;
    const int rows = (row0 + rowsPerChunk <= N) ? rowsPerChunk : (N - row0);
    for (int r = 0; r < rows; ++r) {
        float v = p[(size_t)r * D];
        int   l = labs[r];
        float sq = v * v;
#pragma unroll
        for (int c = 0; c < NCLS; ++c) {
            float m = (l == c) ? 1.0f : 0.0f;
            vacc[c] = fmaf(m, v, vacc[c]);
            sacc[c] = fmaf(m, sq, sacc[c]);
        }
    }
#pragma unroll
    for (int c = 0; c < NCLS; ++c) atomicAdd(&V[c * D + d], vacc[c]);
    const int lane = t & 63;
#pragma unroll
    for (int c = 0; c < NCLS; ++c) {
        float v = wave_reduce64(sacc[c]);
        if (lane == 0) atomicAdd(&Ssq[c], v);
    }
}

__global__ __launch_bounds__(256) void finalize_small_kernel(
        const float* __restrict__ x, const int* __restrict__ label,
        const float* __restrict__ V, const float* __restrict__ Ssq,
        float* __restrict__ result, int N, int D) {
    const int t    = threadIdx.x;
    const int lane = t & 63;
    const int wave = t >> 6;

    float cnt[NCLS];
#pragma unroll
    for (int c = 0; c < NCLS; ++c) cnt[c] = 0.f;
    for (int i = t; i < N; i += 256) {
        int l = label[i];
#pragma unroll
        for (int c = 0; c < NCLS; ++c) cnt[c] += (l == c) ? 1.0f : 0.0f;
    }
    __shared__ float lcnt[4][NCLS];
#pragma unroll
    for (int c = 0; c < NCLS; ++c) {
        float v = wave_reduce64(cnt[c]);
        if (lane == 0) lcnt[wave][c] = v;
    }

    float VV[NCLS], V0[NCLS], VN[NCLS];
#pragma unroll
    for (int c = 0; c < NCLS; ++c) { VV[c] = 0.f; V0[c] = 0.f; VN[c] = 0.f; }
    float VVt = 0.f, d0N = 0.f, s0 = 0.f, sN = 0.f;

    const float* x0 = x;
    const float* xN = x + (size_t)(N - 1) * D;
    for (int d = t; d < D; d += 256) {
        float a0 = x0[d], aN = xN[d];
        float vt = 0.f;
#pragma unroll
        for (int c = 0; c < NCLS; ++c) {
            float v = V[c * D + d];
            VV[c] += v * v;
            V0[c] += v * a0;
            VN[c] += v * aN;
            vt    += v;
        }
        VVt += vt * vt;
        d0N += a0 * aN;
        s0  += a0 * a0;
        sN  += aN * aN;
    }

    float vals[NV3];
#pragma unroll
    for (int c = 0; c < NCLS; ++c) {
        vals[c]      = VV[c];
        vals[10 + c] = V0[c];
        vals[20 + c] = VN[c];
    }
    vals[30] = VVt; vals[31] = d0N; vals[32] = s0; vals[33] = sN;

    __shared__ float red[4][NV3];
#pragma unroll
    for (int k = 0; k < NV3; ++k) {
        float v = wave_reduce64(vals[k]);
        if (lane == 0) red[wave][k] = v;
    }
    __syncthreads();

    if (t == 0) {
        double v[NV3];
        for (int k = 0; k < NV3; ++k)
            v[k] = (double)red[0][k] + (double)red[1][k] + (double)red[2][k] + (double)red[3][k];

        const int l0 = label[0];
        const int lN = label[N - 1];
        const double sq0 = v[32], sqN = v[33], dON = v[31], VVtd = v[30];

        double A = 0.0, SsqTot = 0.0, Vt0 = 0.0, VtN = 0.0;
        for (int c = 0; c < NCLS; ++c) {
            double nc   = (double)(lcnt[0][c] + lcnt[1][c] + lcnt[2][c] + lcnt[3][c]);
            double Ssqc = (double)Ssq[c];
            SsqTot += Ssqc;
            Vt0    += v[10 + c];
            VtN    += v[20 + c];
            double ac = (lN == c) ? 1.0 : 0.0;
            double bc = (l0 == c) ? 1.0 : 0.0;
            double nR = nc - ac, nC = nc - bc;
            double SsqR  = Ssqc - ac * sqN;
            double SsqC  = Ssqc - bc * sq0;
            double dotRC = v[c] - bc * v[10 + c] - ac * v[20 + c] + ac * bc * dON;
            A += nC * SsqR + nR * SsqC - 2.0 * dotRC;
        }
        double Bv = (double)(N - 1) * ((SsqTot - sqN) + (SsqTot - sq0))
                  - 2.0 * (VVtd - Vt0 - VtN + dON);
        double total = 2.0 * A - Bv;
        result[0] = (float)((0.5 / (double)N) * total);
    }
}

extern "C" void kernel_launch(void* const* d_in, const int* in_sizes, int n_in,
                              void* d_out, int out_size, void* d_ws, size_t ws_size,
                              hipStream_t stream) {
    const float* x     = (const float*)d_in[0];
    const int*   label = (const int*)d_in[1];
    const int N = in_sizes[1];
    const int D = in_sizes[0] / N;   // 1024
    float* result = (float*)d_out;

    const size_t wsFloats = ws_size / sizeof(float);
    const int rpb = 128;
    const int S = (D % 64 == 0) ? D / 64 : 0;
    const int G = (N + rpb - 1) / rpb;
    const int gridA = G * S;

    // ws layout (all plain-store fresh each call; no init needed):
    //   Vpart[G*NCLS*D] | Spart[gridA*NCLS] | hist[G*NCLS] i32 |
    //   cntF[16] | slots[(S+1)*SLOTW] | done u32
    size_t off = 0;
    float* Vpart = (float*)d_ws;                 off += (size_t)G * NCLS * D;
    float* Spart = (float*)d_ws + off;           off += (size_t)gridA * NCLS;
    int*   hist  = (int*)((float*)d_ws + off);   off += (size_t)G * NCLS;
    float* cntF  = (float*)d_ws + off;           off += 16;
    float* slots = (float*)d_ws + off;           off += (size_t)(S + 1) * SLOTW;
    unsigned int* done = (unsigned int*)((float*)d_ws + off); off += 1;

    bool ok = (S > 0) && (N >= 2) && (off <= wsFloats) && (G >= 1);

    if (ok) {
        phaseA_kernel<<<gridA, 256, 0, stream>>>(
            x, label, Vpart, Spart, hist, done, N, D, S, rpb);
        finish_kernel<<<S + 1, 256, 0, stream>>>(
            x, label, Vpart, Spart, hist, slots, cntF, done, result,
            N, D, S, G, gridA);
        return;
    }

    // ---- fallback: v1 atomic path (tiny ws / odd D) ----
    float* V   = (float*)d_ws;
    float* Ssq = V + (size_t)NCLS * D;
    const int nz = NCLS * D + NCLS;
    zero_ws_kernel<<<(nz + 255) / 256, 256, 0, stream>>>(V, nz);
    const int rowsPerChunk = 64;
    const int dimSlices = (D + 255) / 256;
    const int rowChunks = (N + rowsPerChunk - 1) / rowsPerChunk;
    accum_kernel<<<rowChunks * dimSlices, 256, 0, stream>>>(
        x, label, V, Ssq, N, D, dimSlices, rowsPerChunk);
    finalize_small_kernel<<<1, 256, 0, stream>>>(x, label, V, Ssq, result, N, D);
}